// Round 1
// baseline (213.053 us; speedup 1.0000x reference)
//
#include <hip/hip_runtime.h>
#include <stdint.h>

#define NTOT   73728
#define KSEL   512
#define DET_THRf 0.7f
#define NMS_THRf 0.7f
#define HFD    32
#define WFD    32
#define CCH    1024
#define IMGF   1024.0f
#define SAMP   14          // ALIGN * SAMPLES
#define FEAT1  256
#define OUTD   84
#define MAXC   4096
#define BUCKETS 256
#define BSCALE 48.0f

// ---------------- workspace layout (bytes) ----------------
#define WS_HIST     0        // int[256]        (1024)
#define WS_CUTB     1024     // int
#define WS_COUNTER  1028     // int
#define WS_CSCORE   1040     // float[MAXC]     (16384)
#define WS_CIDX     17424    // int[MAXC]       (16384)
#define WS_SELIDX   33824    // int[512]        (2048)
#define WS_VALID    35872    // int[512]        (2048)
#define WS_ASSIGN   37920    // int[512]        (2048)
#define WS_ROIS     39968    // float4[512]     (8192)
#define WS_BOXES    48160    // float4[512]     (8192)
#define WS_KEEPF    56352    // float[512]      (2048)
#define WS_SUP      58400    // uint64[512*8]   (32768)  -> total 91168

__device__ __forceinline__ int bucket_of(float s) {
  int b = (int)((s - DET_THRf) * BSCALE);
  return min(max(b, 0), BUCKETS - 1);
}

// -------- K1: histogram of scores > thr --------
__global__ void k_hist(const float* __restrict__ pred, int* __restrict__ hist) {
  __shared__ int lh[BUCKETS];
  int t = threadIdx.x;
  lh[t] = 0;
  __syncthreads();
  for (int i = blockIdx.x * blockDim.x + t; i < NTOT; i += gridDim.x * blockDim.x) {
    float s = pred[i];
    if (s > DET_THRf) atomicAdd(&lh[bucket_of(s)], 1);
  }
  __syncthreads();
  if (lh[t]) atomicAdd(&hist[t], lh[t]);
}

// -------- K2: find cutoff bucket B = max b with count(bucket>=b) >= KSEL --------
__global__ void k_scan(const int* __restrict__ hist, int* __restrict__ cutB) {
  if (threadIdx.x == 0) {
    int cum = 0, B = 0;
    for (int b = BUCKETS - 1; b >= 0; --b) {
      cum += hist[b];
      if (cum >= KSEL) { B = b; break; }
    }
    *cutB = B;
  }
}

// -------- K3: collect candidates with bucket >= B --------
__global__ void k_collect(const float* __restrict__ pred, const int* __restrict__ cutB,
                          int* __restrict__ counter, float* __restrict__ cs,
                          int* __restrict__ ci) {
  int B = *cutB;
  for (int i = blockIdx.x * blockDim.x + threadIdx.x; i < NTOT; i += gridDim.x * blockDim.x) {
    float s = pred[i];
    if (s > DET_THRf && bucket_of(s) >= B) {
      int p = atomicAdd(counter, 1);
      if (p < MAXC) { cs[p] = s; ci[p] = i; }
    }
  }
}

// -------- K4: exact rank -> top-512 in jax.lax.top_k order; gather rois/anchors --------
__global__ void __launch_bounds__(512) k_select(
    const int* __restrict__ counter, const float* __restrict__ cs, const int* __restrict__ ci,
    const float* __restrict__ rois, const float* __restrict__ anchors,
    const int* __restrict__ assign,
    int* __restrict__ sel_idx, int* __restrict__ valid, int* __restrict__ assign_sel,
    float4* __restrict__ rois_sel, float4* __restrict__ boxes_sh) {
  __shared__ float s_s[MAXC];
  __shared__ int   s_i[MAXC];
  int t = threadIdx.x;
  int M = *counter; if (M > MAXC) M = MAXC;
  for (int j = t; j < M; j += 512) { s_s[j] = cs[j]; s_i[j] = ci[j]; }
  if (t < KSEL) { sel_idx[t] = 0; valid[t] = 0; }
  __syncthreads();
  for (int j = t; j < M; j += 512) {
    float sj = s_s[j]; int ij = s_i[j];
    int r = 0;
    for (int m = 0; m < M; ++m) {
      float sm = s_s[m];
      r += (sm > sj) || (sm == sj && s_i[m] < ij);
    }
    if (r < KSEL) { sel_idx[r] = ij; valid[r] = 1; }
  }
  __syncthreads();
  if (t < KSEL) {
    int v = valid[t];
    int gi = v ? sel_idx[t] : 0;
    float4 rr = make_float4(0.f, 0.f, 0.f, 0.f);
    float4 bx = make_float4(0.f, 0.f, 0.f, 0.f);
    int aa = 0;
    if (v) {
      rr = make_float4(rois[gi*4+0], rois[gi*4+1], rois[gi*4+2], rois[gi*4+3]);
      float cy = anchors[gi*4+0], cx = anchors[gi*4+1];
      float h  = anchors[gi*4+2], w  = anchors[gi*4+3];
      aa = assign[gi];
      float off = (float)aa * IMGF;
      bx = make_float4(cy - h*0.5f + off, cx - w*0.5f + off,
                       cy + h*0.5f + off, cx + w*0.5f + off);
    }
    rois_sel[t] = rr;
    boxes_sh[t] = bx;
    assign_sel[t] = aa;
  }
}

// -------- K5: 512x512 IoU>thr bitmask (one wave per row) --------
__global__ void k_ioumat(const float4* __restrict__ boxes,
                         unsigned long long* __restrict__ sup) {
  int wave = (blockIdx.x * blockDim.x + threadIdx.x) >> 6;
  int lane = threadIdx.x & 63;
  if (wave >= KSEL) return;
  float4 bi = boxes[wave];
  float a1 = (bi.z - bi.x) * (bi.w - bi.y);
  for (int c = 0; c < 8; ++c) {
    int col = c * 64 + lane;
    float4 bj = boxes[col];
    float yA = fmaxf(bi.x, bj.x), xA = fmaxf(bi.y, bj.y);
    float yB = fminf(bi.z, bj.z), xB = fminf(bi.w, bj.w);
    float inter = fmaxf(yB - yA, 0.f) * fmaxf(xB - xA, 0.f);
    float a2 = (bj.z - bj.x) * (bj.w - bj.y);
    float iou = inter / (a1 + a2 - inter + 1e-8f);
    bool s = (iou > NMS_THRf) && (col > wave);
    unsigned long long m = __ballot(s);
    if (lane == 0) sup[wave * 8 + c] = m;
  }
}

// -------- K6: sequential NMS sweep over nonzero rows (1 wave) --------
__global__ void k_sweep(const unsigned long long* __restrict__ sup,
                        const int* __restrict__ valid,
                        float* __restrict__ keep_ws, float* __restrict__ keep_out) {
  __shared__ unsigned char kb[KSEL];
  int t = threadIdx.x;  // 64 threads
  for (int j = t; j < KSEL; j += 64) kb[j] = (unsigned char)valid[j];
  // nonzero-row bitmap: lane handles rows w*64+t
  unsigned long long nz[8];
  for (int w = 0; w < 8; ++w) {
    int row = w * 64 + t;
    const unsigned long long* rp = &sup[row * 8];
    unsigned long long any = rp[0]|rp[1]|rp[2]|rp[3]|rp[4]|rp[5]|rp[6]|rp[7];
    nz[w] = __ballot(any != 0ull);
  }
  __syncthreads();
  if (t == 0) {
    for (int w = 0; w < 8; ++w) {
      unsigned long long bits = nz[w];
      while (bits) {
        int b = __ffsll((unsigned long long)bits) - 1;
        bits &= bits - 1;
        int i = w * 64 + b;
        if (kb[i]) {
          const unsigned long long* rp = &sup[i * 8];
          for (int c = 0; c < 8; ++c) {
            unsigned long long m = rp[c];
            while (m) {
              int bb = __ffsll((unsigned long long)m) - 1;
              m &= m - 1;
              kb[c * 64 + bb] = 0;
            }
          }
        }
      }
    }
  }
  __syncthreads();
  for (int j = t; j < KSEL; j += 64) {
    float kf = kb[j] ? 1.0f : 0.0f;
    keep_ws[j] = kf;
    keep_out[j] = kf;
  }
}

// -------- K7: fused separable ROI-align + FC1 + BN + ReLU + FC2 + mask --------
__global__ void __launch_bounds__(256) k_head(
    const float* __restrict__ feats,
    const float* __restrict__ W1, const float* __restrict__ b1,
    const float* __restrict__ gamma, const float* __restrict__ beta,
    const float* __restrict__ mmean, const float* __restrict__ mvar,
    const float* __restrict__ W2, const float* __restrict__ b2,
    const float4* __restrict__ rois_sel, const int* __restrict__ assign_sel,
    const float* __restrict__ keepf_ws,
    float* __restrict__ pred_out, float* __restrict__ rois_out) {
  int r = blockIdx.x;
  int t = threadIdx.x;

  float kf = keepf_ws[r];
  float4 roi = rois_sel[r];
  if (kf == 0.0f) {
    for (int j = t; j < 80; j += 256) pred_out[r * 80 + j] = 0.f;
    if (t < 4) rois_out[r * 4 + t] = 0.f;
    return;
  }

  __shared__ float Wy[HFD], Wx[WFD];
  __shared__ int bnds[4];
  __shared__ float pooled[CCH];
  __shared__ float hdd[FEAT1];
  __shared__ float outv[OUTD];

  if (t < 32) { Wy[t] = 0.f; Wx[t] = 0.f; }
  __syncthreads();
  if (t == 0) {
    float sc = (float)HFD / IMGF;   // feature-space scale (H == W == 32)
    float y1 = roi.x * sc, x1 = roi.y * sc, y2 = roi.z * sc, x2 = roi.w * sc;
    int ymin = HFD - 1, ymax = 0, xmin = WFD - 1, xmax = 0;
    for (int s = 0; s < SAMP; ++s) {
      float fr = ((float)s + 0.5f) / (float)SAMP;
      float yc = y1 + fr * (y2 - y1) - 0.5f;
      yc = fminf(fmaxf(yc, 0.0f), (float)(HFD - 1));
      float y0f = floorf(yc);
      int y0 = (int)y0f;
      int y1i = min(y0 + 1, HFD - 1);
      float wy = yc - y0f;
      Wy[y0] += 1.0f - wy;
      Wy[y1i] += wy;
      ymin = min(ymin, y0); ymax = max(ymax, y1i);

      float xc = x1 + fr * (x2 - x1) - 0.5f;
      xc = fminf(fmaxf(xc, 0.0f), (float)(WFD - 1));
      float x0f = floorf(xc);
      int x0 = (int)x0f;
      int x1i = min(x0 + 1, WFD - 1);
      float wx = xc - x0f;
      Wx[x0] += 1.0f - wx;
      Wx[x1i] += wx;
      xmin = min(xmin, x0); xmax = max(xmax, x1i);
    }
    bnds[0] = ymin; bnds[1] = ymax; bnds[2] = xmin; bnds[3] = xmax;
  }
  __syncthreads();

  int b = assign_sel[r];
  const float4* f4 = (const float4*)feats;
  float4 acc = make_float4(0.f, 0.f, 0.f, 0.f);
  int ymin = bnds[0], ymax = bnds[1], xmin = bnds[2], xmax = bnds[3];
  for (int y = ymin; y <= ymax; ++y) {
    float wyv = Wy[y];
    int rowbase = ((b * HFD + y) * WFD) * (CCH / 4);
    for (int x = xmin; x <= xmax; ++x) {
      float w = wyv * Wx[x];
      float4 v = f4[rowbase + x * (CCH / 4) + t];
      acc.x += w * v.x; acc.y += w * v.y; acc.z += w * v.z; acc.w += w * v.w;
    }
  }
  const float inv = 1.0f / (float)(SAMP * SAMP);
  pooled[4 * t + 0] = acc.x * inv;
  pooled[4 * t + 1] = acc.y * inv;
  pooled[4 * t + 2] = acc.z * inv;
  pooled[4 * t + 3] = acc.w * inv;
  __syncthreads();

  // FC1 (1024 -> 256): thread t computes output feature t
  float h = b1[t];
  #pragma unroll 8
  for (int c = 0; c < CCH; ++c) h += pooled[c] * W1[c * FEAT1 + t];
  h = (h - mmean[t]) * rsqrtf(mvar[t] + 1e-3f) * gamma[t] + beta[t];
  hdd[t] = fmaxf(h, 0.f);
  __syncthreads();

  // FC2 (256 -> 84)
  if (t < OUTD) {
    float o = b2[t];
    #pragma unroll 8
    for (int k = 0; k < FEAT1; ++k) o += hdd[k] * W2[k * OUTD + t];
    outv[t] = o;
  }
  __syncthreads();

  for (int j = t; j < 80; j += 256) pred_out[r * 80 + j] = outv[4 + j] * kf;
  if (t < 4) {
    float rc = (t == 0) ? roi.x : (t == 1) ? roi.y : (t == 2) ? roi.z : roi.w;
    rois_out[r * 4 + t] = (rc + outv[t]) * kf;
  }
}

extern "C" void kernel_launch(void* const* d_in, const int* in_sizes, int n_in,
                              void* d_out, int out_size, void* d_ws, size_t ws_size,
                              hipStream_t stream) {
  const float* pred    = (const float*)d_in[0];
  const float* rois    = (const float*)d_in[1];
  const float* anchors = (const float*)d_in[2];
  const int*   assign  = (const int*)d_in[3];
  const float* feats   = (const float*)d_in[4];
  const float* W1      = (const float*)d_in[5];
  const float* b1      = (const float*)d_in[6];
  const float* gamma   = (const float*)d_in[7];
  const float* beta    = (const float*)d_in[8];
  const float* mmean   = (const float*)d_in[9];
  const float* mvar    = (const float*)d_in[10];
  const float* W2      = (const float*)d_in[11];
  const float* b2      = (const float*)d_in[12];

  char* ws = (char*)d_ws;
  int*   hist     = (int*)(ws + WS_HIST);
  int*   cutB     = (int*)(ws + WS_CUTB);
  int*   counter  = (int*)(ws + WS_COUNTER);
  float* cscore   = (float*)(ws + WS_CSCORE);
  int*   cidx     = (int*)(ws + WS_CIDX);
  int*   sel_idx  = (int*)(ws + WS_SELIDX);
  int*   validp   = (int*)(ws + WS_VALID);
  int*   asel     = (int*)(ws + WS_ASSIGN);
  float4* rois_sel = (float4*)(ws + WS_ROIS);
  float4* boxes_sh = (float4*)(ws + WS_BOXES);
  float* keepf    = (float*)(ws + WS_KEEPF);
  unsigned long long* sup = (unsigned long long*)(ws + WS_SUP);

  float* pred_out = (float*)d_out;               // 512 x 80
  float* rois_out = pred_out + KSEL * 80;        // 512 x 4
  float* keep_out = rois_out + KSEL * 4;         // 512

  hipMemsetAsync(ws, 0, 1040, stream);  // hist + cutB + counter

  k_hist<<<64, BUCKETS, 0, stream>>>(pred, hist);
  k_scan<<<1, 64, 0, stream>>>(hist, cutB);
  k_collect<<<64, 256, 0, stream>>>(pred, cutB, counter, cscore, cidx);
  k_select<<<1, 512, 0, stream>>>(counter, cscore, cidx, rois, anchors, assign,
                                  sel_idx, validp, asel, rois_sel, boxes_sh);
  k_ioumat<<<128, 256, 0, stream>>>(boxes_sh, sup);
  k_sweep<<<1, 64, 0, stream>>>(sup, validp, keepf, keep_out);
  k_head<<<KSEL, 256, 0, stream>>>(feats, W1, b1, gamma, beta, mmean, mvar,
                                   W2, b2, rois_sel, asel, keepf,
                                   pred_out, rois_out);
}

// Round 2
// 212.864 us; speedup vs baseline: 1.0009x; 1.0009x over previous
//
#include <hip/hip_runtime.h>
#include <stdint.h>

#define NTOT   73728
#define KSEL   512
#define DET_THRf 0.7f
#define NMS_THRf 0.7f
#define HFD    32
#define WFD    32
#define CCH    1024
#define IMGF   1024.0f
#define SAMP   14          // ALIGN * SAMPLES
#define FEAT1  256
#define OUTD   84
#define MAXC   4096
#define BUCKETS 256
#define BSCALE 48.0f
#define RB     4           // ROIs per k_fc block

// ---------------- workspace layout (bytes) ----------------
#define WS_HIST     0        // int[256]            (1024)
#define WS_CUTB     1024     // int
#define WS_COUNTER  1028     // int
#define WS_VALID    1032     // int[512]  -> 3080   (memset region 0..3080)
#define WS_SELIDX   3080     // int[512]  -> 5128
#define WS_CSCORE   5136     // float[4096] -> 21520
#define WS_CIDX     21520    // int[4096]   -> 37904
#define WS_ROIS     37904    // float4[512] -> 46096
#define WS_BOXES    46096    // float4[512] -> 54288
#define WS_ASSIGN   54288    // int[512]    -> 56336
#define WS_KEEPF    56336    // float[512]  -> 58384
#define WS_SUP      58384    // u64[512*8]  -> 91152
#define WS_POOLED   91152    // float[512*1024] -> 2188304

__device__ __forceinline__ int bucket_of(float s) {
  int b = (int)((s - DET_THRf) * BSCALE);
  return min(max(b, 0), BUCKETS - 1);
}

// -------- K1: histogram of scores > thr --------
__global__ void k_hist(const float* __restrict__ pred, int* __restrict__ hist) {
  __shared__ int lh[BUCKETS];
  int t = threadIdx.x;
  lh[t] = 0;
  __syncthreads();
  for (int i = blockIdx.x * blockDim.x + t; i < NTOT; i += gridDim.x * blockDim.x) {
    float s = pred[i];
    if (s > DET_THRf) atomicAdd(&lh[bucket_of(s)], 1);
  }
  __syncthreads();
  if (lh[t]) atomicAdd(&hist[t], lh[t]);
}

// -------- K2: parallel suffix-count -> cutoff bucket --------
__global__ void k_scan(const int* __restrict__ hist, int* __restrict__ cutB) {
  __shared__ int sh[BUCKETS];
  __shared__ int best;
  int t = threadIdx.x;
  sh[t] = hist[t];
  if (t == 0) best = -1;
  __syncthreads();
  for (int off = 1; off < BUCKETS; off <<= 1) {
    int v = sh[t] + ((t + off < BUCKETS) ? sh[t + off] : 0);
    __syncthreads();
    sh[t] = v;
    __syncthreads();
  }
  if (sh[t] >= KSEL) atomicMax(&best, t);
  __syncthreads();
  if (t == 0) *cutB = (best < 0) ? 0 : best;
}

// -------- K3: collect candidates with bucket >= B --------
__global__ void k_collect(const float* __restrict__ pred, const int* __restrict__ cutB,
                          int* __restrict__ counter, float* __restrict__ cs,
                          int* __restrict__ ci) {
  int B = *cutB;
  for (int i = blockIdx.x * blockDim.x + threadIdx.x; i < NTOT; i += gridDim.x * blockDim.x) {
    float s = pred[i];
    if (s > DET_THRf && bucket_of(s) >= B) {
      int p = atomicAdd(counter, 1);
      if (p < MAXC) { cs[p] = s; ci[p] = i; }
    }
  }
}

// -------- K4: exact rank per candidate (jax.lax.top_k order) --------
__global__ void __launch_bounds__(256) k_rank(
    const int* __restrict__ counter, const float* __restrict__ cs, const int* __restrict__ ci,
    int* __restrict__ sel_idx, int* __restrict__ valid) {
  __shared__ float s_s[MAXC];
  __shared__ int   s_i[MAXC];
  int t = threadIdx.x;
  int M = *counter; if (M > MAXC) M = MAXC;
  for (int j = t; j < M; j += 256) { s_s[j] = cs[j]; s_i[j] = ci[j]; }
  __syncthreads();
  int j = blockIdx.x * 256 + t;
  if (j >= M) return;
  float sj = s_s[j]; int ij = s_i[j];
  int r = 0;
  for (int m = 0; m < M; ++m) {
    float sm = s_s[m];
    r += (sm > sj) || (sm == sj && s_i[m] < ij);
  }
  if (r < KSEL) { sel_idx[r] = ij; valid[r] = 1; }
}

// -------- K5: gather rois/anchors for selected --------
__global__ void k_gather(const int* __restrict__ sel_idx, const int* __restrict__ valid,
                         const float* __restrict__ rois, const float* __restrict__ anchors,
                         const int* __restrict__ assign,
                         int* __restrict__ assign_sel, float4* __restrict__ rois_sel,
                         float4* __restrict__ boxes_sh) {
  int t = threadIdx.x;
  if (t >= KSEL) return;
  int v = valid[t];
  int gi = v ? sel_idx[t] : 0;
  float4 rr = make_float4(0.f, 0.f, 0.f, 0.f);
  float4 bx = make_float4(0.f, 0.f, 0.f, 0.f);
  int aa = 0;
  if (v) {
    rr = make_float4(rois[gi*4+0], rois[gi*4+1], rois[gi*4+2], rois[gi*4+3]);
    float cy = anchors[gi*4+0], cx = anchors[gi*4+1];
    float h  = anchors[gi*4+2], w  = anchors[gi*4+3];
    aa = assign[gi];
    float off = (float)aa * IMGF;
    bx = make_float4(cy - h*0.5f + off, cx - w*0.5f + off,
                     cy + h*0.5f + off, cx + w*0.5f + off);
  }
  rois_sel[t] = rr;
  boxes_sh[t] = bx;
  assign_sel[t] = aa;
}

// -------- K6: 512x512 IoU>thr bitmask (one wave per row) --------
__global__ void k_ioumat(const float4* __restrict__ boxes,
                         unsigned long long* __restrict__ sup) {
  int wave = (blockIdx.x * blockDim.x + threadIdx.x) >> 6;
  int lane = threadIdx.x & 63;
  if (wave >= KSEL) return;
  float4 bi = boxes[wave];
  float a1 = (bi.z - bi.x) * (bi.w - bi.y);
  for (int c = 0; c < 8; ++c) {
    int col = c * 64 + lane;
    float4 bj = boxes[col];
    float yA = fmaxf(bi.x, bj.x), xA = fmaxf(bi.y, bj.y);
    float yB = fminf(bi.z, bj.z), xB = fminf(bi.w, bj.w);
    float inter = fmaxf(yB - yA, 0.f) * fmaxf(xB - xA, 0.f);
    float a2 = (bj.z - bj.x) * (bj.w - bj.y);
    float iou = inter / (a1 + a2 - inter + 1e-8f);
    bool s = (iou > NMS_THRf) && (col > wave);
    unsigned long long m = __ballot(s);
    if (lane == 0) sup[wave * 8 + c] = m;
  }
}

// -------- K7: sequential NMS sweep over nonzero rows (1 wave) --------
__global__ void k_sweep(const unsigned long long* __restrict__ sup,
                        const int* __restrict__ valid,
                        float* __restrict__ keep_ws, float* __restrict__ keep_out) {
  __shared__ unsigned char kb[KSEL];
  int t = threadIdx.x;  // 64 threads
  for (int j = t; j < KSEL; j += 64) kb[j] = (unsigned char)valid[j];
  unsigned long long nz[8];
  for (int w = 0; w < 8; ++w) {
    int row = w * 64 + t;
    const unsigned long long* rp = &sup[row * 8];
    unsigned long long any = rp[0]|rp[1]|rp[2]|rp[3]|rp[4]|rp[5]|rp[6]|rp[7];
    nz[w] = __ballot(any != 0ull);
  }
  __syncthreads();
  if (t == 0) {
    for (int w = 0; w < 8; ++w) {
      unsigned long long bits = nz[w];
      while (bits) {
        int b = __ffsll((unsigned long long)bits) - 1;
        bits &= bits - 1;
        int i = w * 64 + b;
        if (kb[i]) {
          const unsigned long long* rp = &sup[i * 8];
          for (int c = 0; c < 8; ++c) {
            unsigned long long m = rp[c];
            while (m) {
              int bb = __ffsll((unsigned long long)m) - 1;
              m &= m - 1;
              kb[c * 64 + bb] = 0;
            }
          }
        }
      }
    }
  }
  __syncthreads();
  for (int j = t; j < KSEL; j += 64) {
    float kf = kb[j] ? 1.0f : 0.0f;
    keep_ws[j] = kf;
    keep_out[j] = kf;
  }
}

// -------- K8: separable ROI-align with pixel list + 4-way MLP --------
__global__ void __launch_bounds__(256) k_pool(
    const float* __restrict__ feats,
    const float4* __restrict__ rois_sel, const int* __restrict__ assign_sel,
    float* __restrict__ pooled) {
  int r = blockIdx.x;
  int t = threadIdx.x;

  __shared__ float Wy[HFD], Wx[WFD];
  __shared__ int bnds[4];
  __shared__ float wcomb[128];
  __shared__ int   ocomb[128];

  if (t < 32) { Wy[t] = 0.f; Wx[t] = 0.f; }
  __syncthreads();
  if (t == 0) {
    float4 roi = rois_sel[r];
    float sc = (float)HFD / IMGF;
    float y1 = roi.x * sc, x1 = roi.y * sc, y2 = roi.z * sc, x2 = roi.w * sc;
    int ymin = HFD - 1, ymax = 0, xmin = WFD - 1, xmax = 0;
    for (int s = 0; s < SAMP; ++s) {
      float fr = ((float)s + 0.5f) / (float)SAMP;
      float yc = y1 + fr * (y2 - y1) - 0.5f;
      yc = fminf(fmaxf(yc, 0.0f), (float)(HFD - 1));
      float y0f = floorf(yc);
      int y0 = (int)y0f;
      int y1i = min(y0 + 1, HFD - 1);
      float wy = yc - y0f;
      Wy[y0] += 1.0f - wy;
      Wy[y1i] += wy;
      ymin = min(ymin, y0); ymax = max(ymax, y1i);

      float xc = x1 + fr * (x2 - x1) - 0.5f;
      xc = fminf(fmaxf(xc, 0.0f), (float)(WFD - 1));
      float x0f = floorf(xc);
      int x0 = (int)x0f;
      int x1i = min(x0 + 1, WFD - 1);
      float wx = xc - x0f;
      Wx[x0] += 1.0f - wx;
      Wx[x1i] += wx;
      xmin = min(xmin, x0); xmax = max(xmax, x1i);
    }
    bnds[0] = ymin; bnds[1] = ymax; bnds[2] = xmin; bnds[3] = xmax;
  }
  __syncthreads();

  int ymin = bnds[0], xmin = bnds[2];
  int spanY = bnds[1] - ymin + 1;
  int spanX = bnds[3] - xmin + 1;
  int np = spanY * spanX;
  int b = assign_sel[r];
  const float inv = 1.0f / (float)(SAMP * SAMP);

  int ty = t >> 4, tx = t & 15;
  if (ty < spanY && tx < spanX) {
    int p = ty * spanX + tx;
    int y = ymin + ty, x = xmin + tx;
    wcomb[p] = Wy[y] * Wx[x] * inv;
    ocomb[p] = ((b * HFD + y) * WFD + x) * (CCH / 4);
  }
  __syncthreads();

  const float4* f4 = (const float4*)feats;
  float4 a0 = make_float4(0.f,0.f,0.f,0.f), a1 = a0, a2 = a0, a3 = a0;
  int p = 0;
  for (; p + 4 <= np; p += 4) {
    float w0 = wcomb[p],   w1 = wcomb[p+1], w2 = wcomb[p+2], w3 = wcomb[p+3];
    int   o0 = ocomb[p],   o1 = ocomb[p+1], o2 = ocomb[p+2], o3 = ocomb[p+3];
    float4 v0 = f4[o0 + t], v1 = f4[o1 + t], v2 = f4[o2 + t], v3 = f4[o3 + t];
    a0.x += w0*v0.x; a0.y += w0*v0.y; a0.z += w0*v0.z; a0.w += w0*v0.w;
    a1.x += w1*v1.x; a1.y += w1*v1.y; a1.z += w1*v1.z; a1.w += w1*v1.w;
    a2.x += w2*v2.x; a2.y += w2*v2.y; a2.z += w2*v2.z; a2.w += w2*v2.w;
    a3.x += w3*v3.x; a3.y += w3*v3.y; a3.z += w3*v3.z; a3.w += w3*v3.w;
  }
  for (; p < np; ++p) {
    float w = wcomb[p];
    float4 v = f4[ocomb[p] + t];
    a0.x += w*v.x; a0.y += w*v.y; a0.z += w*v.z; a0.w += w*v.w;
  }
  float4 s;
  s.x = (a0.x + a1.x) + (a2.x + a3.x);
  s.y = (a0.y + a1.y) + (a2.y + a3.y);
  s.z = (a0.z + a1.z) + (a2.z + a3.z);
  s.w = (a0.w + a1.w) + (a2.w + a3.w);
  ((float4*)pooled)[r * (CCH / 4) + t] = s;
}

// -------- K9: FC1+BN+ReLU+FC2+mask, 4 ROIs per block --------
__global__ void __launch_bounds__(256) k_fc(
    const float* __restrict__ pooled,
    const float* __restrict__ W1, const float* __restrict__ b1,
    const float* __restrict__ gamma, const float* __restrict__ beta,
    const float* __restrict__ mmean, const float* __restrict__ mvar,
    const float* __restrict__ W2, const float* __restrict__ b2,
    const float4* __restrict__ rois_sel, const float* __restrict__ keepf,
    float* __restrict__ pred_out, float* __restrict__ rois_out) {
  int r0 = blockIdx.x * RB;
  int t = threadIdx.x;
  __shared__ float hdd[RB][FEAT1];
  __shared__ float outv[RB][OUTD];

  const float* p0 = pooled + (r0 + 0) * CCH;
  const float* p1 = pooled + (r0 + 1) * CCH;
  const float* p2 = pooled + (r0 + 2) * CCH;
  const float* p3 = pooled + (r0 + 3) * CCH;

  float acc0 = 0.f, acc1 = 0.f, acc2 = 0.f, acc3 = 0.f;
  for (int c = 0; c < CCH; c += 4) {
    #pragma unroll
    for (int u = 0; u < 4; ++u) {
      float w = W1[(c + u) * FEAT1 + t];
      acc0 += p0[c + u] * w;
      acc1 += p1[c + u] * w;
      acc2 += p2[c + u] * w;
      acc3 += p3[c + u] * w;
    }
  }
  float bb = b1[t];
  float mn = mmean[t];
  float iv = rsqrtf(mvar[t] + 1e-3f) * gamma[t];
  float bt = beta[t];
  hdd[0][t] = fmaxf((acc0 + bb - mn) * iv + bt, 0.f);
  hdd[1][t] = fmaxf((acc1 + bb - mn) * iv + bt, 0.f);
  hdd[2][t] = fmaxf((acc2 + bb - mn) * iv + bt, 0.f);
  hdd[3][t] = fmaxf((acc3 + bb - mn) * iv + bt, 0.f);
  __syncthreads();

  for (int idx = t; idx < RB * OUTD; idx += 256) {
    int r = idx / OUTD, o = idx - OUTD * r;
    float s = b2[o];
    for (int k = 0; k < FEAT1; k += 4) {
      float4 h4 = *(const float4*)&hdd[r][k];
      s += h4.x * W2[(k+0) * OUTD + o];
      s += h4.y * W2[(k+1) * OUTD + o];
      s += h4.z * W2[(k+2) * OUTD + o];
      s += h4.w * W2[(k+3) * OUTD + o];
    }
    outv[r][o] = s;
  }
  __syncthreads();

  for (int idx = t; idx < RB * 80; idx += 256) {
    int r = idx / 80, j = idx - 80 * r;
    pred_out[(r0 + r) * 80 + j] = outv[r][4 + j] * keepf[r0 + r];
  }
  if (t < RB * 4) {
    int r = t >> 2, c = t & 3;
    float4 roi = rois_sel[r0 + r];
    float rc = (c == 0) ? roi.x : (c == 1) ? roi.y : (c == 2) ? roi.z : roi.w;
    rois_out[(r0 + r) * 4 + c] = (rc + outv[r][c]) * keepf[r0 + r];
  }
}

extern "C" void kernel_launch(void* const* d_in, const int* in_sizes, int n_in,
                              void* d_out, int out_size, void* d_ws, size_t ws_size,
                              hipStream_t stream) {
  const float* pred    = (const float*)d_in[0];
  const float* rois    = (const float*)d_in[1];
  const float* anchors = (const float*)d_in[2];
  const int*   assign  = (const int*)d_in[3];
  const float* feats   = (const float*)d_in[4];
  const float* W1      = (const float*)d_in[5];
  const float* b1      = (const float*)d_in[6];
  const float* gamma   = (const float*)d_in[7];
  const float* beta    = (const float*)d_in[8];
  const float* mmean   = (const float*)d_in[9];
  const float* mvar    = (const float*)d_in[10];
  const float* W2      = (const float*)d_in[11];
  const float* b2      = (const float*)d_in[12];

  char* ws = (char*)d_ws;
  int*   hist     = (int*)(ws + WS_HIST);
  int*   cutB     = (int*)(ws + WS_CUTB);
  int*   counter  = (int*)(ws + WS_COUNTER);
  int*   validp   = (int*)(ws + WS_VALID);
  int*   sel_idx  = (int*)(ws + WS_SELIDX);
  float* cscore   = (float*)(ws + WS_CSCORE);
  int*   cidx     = (int*)(ws + WS_CIDX);
  float4* rois_sel = (float4*)(ws + WS_ROIS);
  float4* boxes_sh = (float4*)(ws + WS_BOXES);
  int*   asel     = (int*)(ws + WS_ASSIGN);
  float* keepf    = (float*)(ws + WS_KEEPF);
  unsigned long long* sup = (unsigned long long*)(ws + WS_SUP);
  float* pooled   = (float*)(ws + WS_POOLED);

  float* pred_out = (float*)d_out;               // 512 x 80
  float* rois_out = pred_out + KSEL * 80;        // 512 x 4
  float* keep_out = rois_out + KSEL * 4;         // 512

  hipMemsetAsync(ws, 0, 3080, stream);  // hist + cutB + counter + valid

  k_hist<<<64, BUCKETS, 0, stream>>>(pred, hist);
  k_scan<<<1, BUCKETS, 0, stream>>>(hist, cutB);
  k_collect<<<64, 256, 0, stream>>>(pred, cutB, counter, cscore, cidx);
  k_rank<<<MAXC / 256, 256, 0, stream>>>(counter, cscore, cidx, sel_idx, validp);
  k_gather<<<1, KSEL, 0, stream>>>(sel_idx, validp, rois, anchors, assign,
                                   asel, rois_sel, boxes_sh);
  k_ioumat<<<128, 256, 0, stream>>>(boxes_sh, sup);
  k_sweep<<<1, 64, 0, stream>>>(sup, validp, keepf, keep_out);
  k_pool<<<KSEL, 256, 0, stream>>>(feats, rois_sel, asel, pooled);
  k_fc<<<KSEL / RB, 256, 0, stream>>>(pooled, W1, b1, gamma, beta, mmean, mvar,
                                      W2, b2, rois_sel, keepf,
                                      pred_out, rois_out);
}